// Round 11
// baseline (99.424 us; speedup 1.0000x reference)
//
#include <hip/hip_runtime.h>
#include <hip/hip_bf16.h>

#define NB 8192   // batch
#define ND 512    // feature dim
#define NC 512    // num classes
#define NCT 8     // number of column tiles (NC / 64)
#define MARGIN_F 1.0f
#define BIGF 3.0e38f

typedef __attribute__((ext_vector_type(8))) short bf16x8;
typedef __attribute__((ext_vector_type(4))) float f32x4;

__device__ __forceinline__ unsigned fkey(float f) {
    unsigned u = __float_as_uint(f);
    unsigned mask = (u & 0x80000000u) ? 0xFFFFFFFFu : 0x80000000u;
    return u ^ mask;
}
__device__ __forceinline__ float finv(unsigned k) {
    unsigned mask = (k & 0x80000000u) ? 0x80000000u : 0xFFFFFFFFu;
    return __uint_as_float(k ^ mask);
}
__device__ __forceinline__ unsigned short f2bf(float f) {
    __hip_bfloat16 h = __float2bfloat16(f);
    return __builtin_bit_cast(unsigned short, h);
}

#define GLOAD_LDS16(g, l)                                                    \
    __builtin_amdgcn_global_load_lds(                                        \
        (const __attribute__((address_space(1))) void*)(g),                  \
        (__attribute__((address_space(3))) void*)(l), 16, 0, 0)

// -------------------------------------------------------------------------
// k0: fp32->bf16 convert (inputs + centers), row/center sqnorms, class
//     histogram. grid = 2177 x 256. (Proven structure.)
// -------------------------------------------------------------------------
__global__ __launch_bounds__(256) void k0_prep(
    const float* __restrict__ inputs, const int* __restrict__ targets,
    const float* __restrict__ centers,
    unsigned short* __restrict__ inB, unsigned short* __restrict__ cenB,
    float* __restrict__ rsq, float* __restrict__ csq,
    unsigned* __restrict__ counts)
{
    const int bid = blockIdx.x;
    const int tid = threadIdx.x;

    if (bid == 2176) {   // histogram block
        __shared__ unsigned hist[NC];
        for (int i = tid; i < NC; i += 256) hist[i] = 0u;
        __syncthreads();
        for (int i = tid; i < NB; i += 256) atomicAdd(&hist[targets[i]], 1u);
        __syncthreads();
        for (int i = tid; i < NC; i += 256) counts[i] = hist[i];
        return;
    }

    const int wave = tid >> 6, lane = tid & 63;
    const float* src;
    unsigned short* dst;
    float* sqdst;
    int row;
    bool is_input = (bid < 2048);
    if (is_input) {
        row   = bid * 4 + wave;
        src   = inputs + (size_t)row * ND;
        dst   = inB + (size_t)row * ND;
        sqdst = rsq + row;
    } else {
        row   = (bid - 2048) * 4 + wave;
        src   = centers + (size_t)row * ND;
        dst   = cenB + (size_t)row * ND;
        sqdst = csq + row;
    }

    float4 v1 = ((const float4*)src)[lane];
    float4 v2 = ((const float4*)src)[lane + 64];
    float s = v1.x*v1.x + v1.y*v1.y + v1.z*v1.z + v1.w*v1.w
            + v2.x*v2.x + v2.y*v2.y + v2.z*v2.z + v2.w*v2.w;

    ushort4 o1, o2;
    o1.x = f2bf(v1.x); o1.y = f2bf(v1.y); o1.z = f2bf(v1.z); o1.w = f2bf(v1.w);
    o2.x = f2bf(v2.x); o2.y = f2bf(v2.y); o2.z = f2bf(v2.z); o2.w = f2bf(v2.w);
    ((ushort4*)dst)[lane]      = o1;
    ((ushort4*)dst)[lane + 64] = o2;

    #pragma unroll
    for (int off = 32; off > 0; off >>= 1) s += __shfl_down(s, off);
    if (lane == 0) *sqdst = s;
}

// -------------------------------------------------------------------------
// k2: bf16 MFMA GEMM + masked-min epilogue. BM=BN=64, BK=64, 256 threads =
// 4 waves in 2x2 (wave tile 32x32). grid = 1024 = 128 rtiles x 8 ctiles
// (rtile = bid&127 -> XCD-local A reuse), 4 blocks/CU.
// DOUBLE-BUFFERED LDS, ONE barrier per iter: loads for tile k+1 issue right
// after the barrier that publishes tile k, so the implicit vmcnt(0) of the
// NEXT barrier drains loads that have had a full compute phase to land.
// LDS in fragment order via global_load_lds -> conflict-free b128 reads.
// -------------------------------------------------------------------------
__global__ __launch_bounds__(256) void k2_mfma(
    const unsigned short* __restrict__ Ain, const unsigned short* __restrict__ cenB,
    const int* __restrict__ targets, const unsigned* __restrict__ counts,
    const float* __restrict__ csq,
    float* __restrict__ partmin, float* __restrict__ apval)
{
    // Per buffer: A = 8 chunks (4 row-groups x 2 k-halves) x 512 shorts,
    // B likewise. Chunk slot lane*8 holds (row = lane&15, k = (lane>>4)*8..+8).
    __shared__ __align__(16) unsigned short As[2][8 * 512];   // 2 x 8 KB
    __shared__ __align__(16) unsigned short Bs[2][8 * 512];   // 2 x 8 KB
    __shared__ int      tgtL[64];
    __shared__ float    csqL[64];
    __shared__ unsigned ldsmin[64];

    const int tid  = threadIdx.x;
    const int w    = tid >> 6;
    const int lane = tid & 63;
    const int wm   = w >> 1;      // 0..1 : 32-row half
    const int wn   = w & 1;       // 0..1 : 32-col half
    const int ln   = lane & 15;
    const int qd   = lane >> 4;

    const int bid   = blockIdx.x;
    const int rbase = (bid & 127) * 64;   // rtile fastest -> rtile%8 pins XCD
    const int ct    = bid >> 7;           // 0..7
    const int cbase = ct * 64;

    if (tid < 64) {
        tgtL[tid]   = targets[rbase + tid];
        const int c = cbase + tid;
        csqL[tid]   = (counts[c] > 0u) ? csq[c] : BIGF;  // empty class never wins
        ldsmin[tid] = 0xFFFFFFFFu;
    }

    // Staging: wave w stages A chunks {2w, 2w+1} and B chunks {2w, 2w+1}.
    const unsigned short* gAp[2];
    const unsigned short* gBp[2];
    int cidL[2];
    #pragma unroll
    for (int t = 0; t < 2; ++t) {
        cidL[t] = 2 * w + t;
        gAp[t] = Ain  + (size_t)(rbase + w * 16 + ln) * ND + t * 32 + qd * 8;
        gBp[t] = cenB + (size_t)(cbase + w * 16 + ln) * ND + t * 32 + qd * 8;
    }

    // Prologue: stage K-tile 0 into buffer 0.
    #pragma unroll
    for (int t = 0; t < 2; ++t) {
        GLOAD_LDS16(gAp[t], &As[0][cidL[t] * 512]);
        GLOAD_LDS16(gBp[t], &Bs[0][cidL[t] * 512]);
    }

    f32x4 acc[2][2] = {};   // 2 row-frags x 2 col-frags of 16x16

    #pragma unroll
    for (int kbi = 0; kbi < 8; ++kbi) {
        const int cur = kbi & 1;
        // Implicit vmcnt(0) here drains loads issued BEFORE the previous
        // compute phase; also proves all waves finished reading buf[cur^1].
        __syncthreads();

        if (kbi < 7) {   // prefetch K-tile kbi+1 into the other buffer
            const int kb = (kbi + 1) * 64;
            #pragma unroll
            for (int t = 0; t < 2; ++t) {
                GLOAD_LDS16(gAp[t] + kb, &As[cur ^ 1][cidL[t] * 512]);
                GLOAD_LDS16(gBp[t] + kb, &Bs[cur ^ 1][cidL[t] * 512]);
            }
        }

        #pragma unroll
        for (int ks = 0; ks < 2; ++ks) {
            bf16x8 a[2], b[2];
            #pragma unroll
            for (int i = 0; i < 2; ++i)
                a[i] = *(const bf16x8*)&As[cur][((wm * 2 + i) * 2 + ks) * 512 + lane * 8];
            #pragma unroll
            for (int j = 0; j < 2; ++j)
                b[j] = *(const bf16x8*)&Bs[cur][((wn * 2 + j) * 2 + ks) * 512 + lane * 8];
            #pragma unroll
            for (int i = 0; i < 2; ++i)
                #pragma unroll
                for (int j = 0; j < 2; ++j)
                    acc[i][j] = __builtin_amdgcn_mfma_f32_16x16x32_bf16(a[i], b[j], acc[i][j], 0, 0, 0);
        }
    }

    // Epilogue. C/D layout: col = lane&15, row = (lane>>4)*4 + reg.
    #pragma unroll
    for (int i = 0; i < 2; ++i) {
        #pragma unroll
        for (int r = 0; r < 4; ++r) {
            const int rlocal = wm * 32 + i * 16 + qd * 4 + r;
            const int grow   = rbase + rlocal;
            const int tr     = tgtL[rlocal];
            float m = BIGF;
            #pragma unroll
            for (int j = 0; j < 2; ++j) {
                const int clocal = wn * 32 + j * 16 + ln;
                const float val = csqL[clocal] - 2.0f * acc[i][j][r];
                if (cbase + clocal == tr) {
                    apval[grow] = val;                 // exactly one writer per row
                } else {
                    m = fminf(m, val);
                }
            }
            #pragma unroll
            for (int off = 1; off < 16; off <<= 1)     // min over 16 cols in-wave
                m = fminf(m, __shfl_xor(m, off));
            if (ln == 0) atomicMin(&ldsmin[rlocal], fkey(m));
        }
    }
    __syncthreads();
    if (tid < 64)
        partmin[(size_t)(rbase + tid) * NCT + ct] = finv(ldsmin[tid]);  // plain store
}

// -------------------------------------------------------------------------
// k3: finalize + reduce, single block. partmin rows are contiguous 8-float
// runs -> two float4 loads per row, fully coalesced.
// -------------------------------------------------------------------------
__global__ __launch_bounds__(1024) void k3_final(
    const float* __restrict__ rsq, const float* __restrict__ partmin,
    const float* __restrict__ apval, float* __restrict__ out)
{
    __shared__ float sl[1024];
    __shared__ float sp[1024];
    const int tid = threadIdx.x;
    float a = 0.0f, p = 0.0f;
    #pragma unroll
    for (int it = 0; it < NB / 1024; ++it) {
        const int r = it * 1024 + tid;
        const float4* pm = (const float4*)&partmin[(size_t)r * NCT];
        float4 m0 = pm[0], m1 = pm[1];
        float m = fminf(fminf(fminf(m0.x, m0.y), fminf(m0.z, m0.w)),
                        fminf(fminf(m1.x, m1.y), fminf(m1.z, m1.w)));
        float s  = rsq[r];
        float an = sqrtf(fmaxf(s + m,        1e-12f));
        float ap = sqrtf(fmaxf(s + apval[r], 1e-12f));
        a += fmaxf(0.0f, ap - an + MARGIN_F);
        p += (an > ap) ? 1.0f : 0.0f;
    }
    sl[tid] = a; sp[tid] = p;
    __syncthreads();
    #pragma unroll
    for (int s = 512; s > 0; s >>= 1) {
        if (tid < s) { sl[tid] += sl[tid + s]; sp[tid] += sp[tid + s]; }
        __syncthreads();
    }
    if (tid == 0) {
        out[0] = sl[0] / (float)NB;
        out[1] = sp[0] / (float)NB;
    }
}

extern "C" void kernel_launch(void* const* d_in, const int* in_sizes, int n_in,
                              void* d_out, int out_size, void* d_ws, size_t ws_size,
                              hipStream_t stream) {
    const float* inputs  = (const float*)d_in[0];
    const int*   targets = (const int*)d_in[1];
    const float* centers = (const float*)d_in[2];
    float* out = (float*)d_out;

    // ws layout (bytes):
    char* wp = (char*)d_ws;
    unsigned short* inB     = (unsigned short*)(wp);             // 8192*512*2 = 8388608
    unsigned short* cenB    = (unsigned short*)(wp + 8388608);   // 512*512*2  = 524288
    float*          rsq     = (float*)(wp + 8912896);            // 8192*4
    float*          csqv    = (float*)(wp + 8945664);            // 512*4
    unsigned*       counts  = (unsigned*)(wp + 8947712);         // 512*4
    float*          apval   = (float*)(wp + 8949760);            // 8192*4
    float*          partmin = (float*)(wp + 8982528);            // 8192*8*4 = 262144

    k0_prep<<<2177, 256, 0, stream>>>(inputs, targets, centers,
                                      inB, cenB, rsq, csqv, counts);
    k2_mfma<<<1024, 256, 0, stream>>>(inB, cenB, targets, counts, csqv,
                                      partmin, apval);
    k3_final<<<1, 1024, 0, stream>>>(rsq, partmin, apval, out);
}

// Round 12
// 93.068 us; speedup vs baseline: 1.0683x; 1.0683x over previous
//
#include <hip/hip_runtime.h>
#include <hip/hip_bf16.h>

#define NB 8192   // batch
#define ND 512    // feature dim
#define NC 512    // num classes
#define NCT 8     // column tiles (NC / 64)
#define MARGIN_F 1.0f
#define BIGF 3.0e38f

typedef __attribute__((ext_vector_type(8))) short bf16x8;
typedef __attribute__((ext_vector_type(4))) float f32x4;

__device__ __forceinline__ unsigned fkey(float f) {
    unsigned u = __float_as_uint(f);
    unsigned mask = (u & 0x80000000u) ? 0xFFFFFFFFu : 0x80000000u;
    return u ^ mask;
}
__device__ __forceinline__ float finv(unsigned k) {
    unsigned mask = (k & 0x80000000u) ? 0x80000000u : 0xFFFFFFFFu;
    return __uint_as_float(k ^ mask);
}
__device__ __forceinline__ unsigned short f2bf(float f) {
    __hip_bfloat16 h = __float2bfloat16(f);
    return __builtin_bit_cast(unsigned short, h);
}

#define GLOAD_LDS16(g, l)                                                    \
    __builtin_amdgcn_global_load_lds(                                        \
        (const __attribute__((address_space(1))) void*)(g),                  \
        (__attribute__((address_space(3))) void*)(l), 16, 0, 0)

// -------------------------------------------------------------------------
// k0: fp32->bf16 convert (inputs + centers), row/center sqnorms, class
//     histogram. grid = 2177 x 256. (R2/R7-proven structure; no negmin init.)
// -------------------------------------------------------------------------
__global__ __launch_bounds__(256) void k0_prep(
    const float* __restrict__ inputs, const int* __restrict__ targets,
    const float* __restrict__ centers,
    unsigned short* __restrict__ inB, unsigned short* __restrict__ cenB,
    float* __restrict__ rsq, float* __restrict__ csq,
    unsigned* __restrict__ counts)
{
    const int bid = blockIdx.x;
    const int tid = threadIdx.x;

    if (bid == 2176) {   // histogram block
        __shared__ unsigned hist[NC];
        for (int i = tid; i < NC; i += 256) hist[i] = 0u;
        __syncthreads();
        for (int i = tid; i < NB; i += 256) atomicAdd(&hist[targets[i]], 1u);
        __syncthreads();
        for (int i = tid; i < NC; i += 256) counts[i] = hist[i];
        return;
    }

    const int wave = tid >> 6, lane = tid & 63;
    const float* src;
    unsigned short* dst;
    float* sqdst;
    int row;
    bool is_input = (bid < 2048);
    if (is_input) {
        row   = bid * 4 + wave;
        src   = inputs + (size_t)row * ND;
        dst   = inB + (size_t)row * ND;
        sqdst = rsq + row;
    } else {
        row   = (bid - 2048) * 4 + wave;
        src   = centers + (size_t)row * ND;
        dst   = cenB + (size_t)row * ND;
        sqdst = csq + row;
    }

    float4 v1 = ((const float4*)src)[lane];
    float4 v2 = ((const float4*)src)[lane + 64];
    float s = v1.x*v1.x + v1.y*v1.y + v1.z*v1.z + v1.w*v1.w
            + v2.x*v2.x + v2.y*v2.y + v2.z*v2.z + v2.w*v2.w;

    ushort4 o1, o2;
    o1.x = f2bf(v1.x); o1.y = f2bf(v1.y); o1.z = f2bf(v1.z); o1.w = f2bf(v1.w);
    o2.x = f2bf(v2.x); o2.y = f2bf(v2.y); o2.z = f2bf(v2.z); o2.w = f2bf(v2.w);
    ((ushort4*)dst)[lane]      = o1;
    ((ushort4*)dst)[lane + 64] = o2;

    #pragma unroll
    for (int off = 32; off > 0; off >>= 1) s += __shfl_down(s, off);
    if (lane == 0) *sqdst = s;
}

// -------------------------------------------------------------------------
// k2: R7's exact GEMM body (best measured: BM=128, BN=64, BK=32, 256 thr =
// 4 waves in 2x2, wave tile 64x32, m97-pattern global_load_lds loop,
// 512 blocks = 64 rtiles x 8 ctiles, rtile-fastest for XCD-local A reuse),
// with R10's plain partmin stores in place of global atomicMin.
// -------------------------------------------------------------------------
__global__ __launch_bounds__(256) void k2_mfma(
    const unsigned short* __restrict__ Ain, const unsigned short* __restrict__ cenB,
    const int* __restrict__ targets, const unsigned* __restrict__ counts,
    const float* __restrict__ csq,
    float* __restrict__ partmin, float* __restrict__ apval)
{
    __shared__ __align__(16) unsigned short As[128 * 32];  // no pad: global_load_lds layout
    __shared__ __align__(16) unsigned short Bs[64 * 32];
    __shared__ int      tgtL[128];
    __shared__ float    csqL[64];
    __shared__ unsigned ldsmin[128];

    const int tid  = threadIdx.x;
    const int w    = tid >> 6;
    const int lane = tid & 63;
    const int wm   = w >> 1;      // 0..1 : 64-row half
    const int wn   = w & 1;       // 0..1 : 32-col half
    const int qd   = lane >> 4;   // quad 0..3
    const int ln   = lane & 15;

    const int bid   = blockIdx.x;
    const int rbase = (bid & 63) * 128;
    const int ct    = bid >> 6;           // 0..7
    const int cbase = ct * 64;

    if (tid < 128) { tgtL[tid] = targets[rbase + tid]; ldsmin[tid] = 0xFFFFFFFFu; }
    if (tid < 64) {
        const int c = cbase + tid;
        csqL[tid] = (counts[c] > 0u) ? csq[c] : BIGF;   // empty class never wins min
    }

    // Staging map (wave-uniform LDS base + lane*16B, m97 pattern):
    // A: wave w stages rows [w*32, w*32+32) in two 16-row chunks.
    // B: wave w stages rows [w*16, w*16+16).
    const int arow0 = w * 32 + (lane >> 2);
    const int brow  = w * 16 + (lane >> 2);
    const int scol  = (lane & 3) * 8;
    const unsigned short* gA0 = Ain  + (size_t)(rbase + arow0)      * ND + scol;
    const unsigned short* gA1 = Ain  + (size_t)(rbase + arow0 + 16) * ND + scol;
    const unsigned short* gB  = cenB + (size_t)(cbase + brow)       * ND + scol;
    unsigned short* lA0 = &As[(w * 32)      * 32];
    unsigned short* lA1 = &As[(w * 32 + 16) * 32];
    unsigned short* lB  = &Bs[(w * 16)      * 32];

    f32x4 acc[4][2] = {};   // 4 row-frags x 2 col-frags of 16x16

    for (int kb = 0; kb < ND; kb += 32) {
        __syncthreads();                       // prev iter's ds_reads done
        GLOAD_LDS16(gA0 + kb, lA0);
        GLOAD_LDS16(gA1 + kb, lA1);
        GLOAD_LDS16(gB  + kb, lB);
        __syncthreads();                       // drains vmcnt -> tile visible

        bf16x8 a[4], b[2];
        #pragma unroll
        for (int i = 0; i < 4; ++i)
            a[i] = *(const bf16x8*)&As[(wm * 64 + i * 16 + ln) * 32 + qd * 8];
        #pragma unroll
        for (int j = 0; j < 2; ++j)
            b[j] = *(const bf16x8*)&Bs[(wn * 32 + j * 16 + ln) * 32 + qd * 8];
        #pragma unroll
        for (int i = 0; i < 4; ++i)
            #pragma unroll
            for (int j = 0; j < 2; ++j)
                acc[i][j] = __builtin_amdgcn_mfma_f32_16x16x32_bf16(a[i], b[j], acc[i][j], 0, 0, 0);
    }

    // Epilogue. C/D layout: col = lane&15, row = (lane>>4)*4 + reg.
    #pragma unroll
    for (int i = 0; i < 4; ++i) {
        #pragma unroll
        for (int r = 0; r < 4; ++r) {
            const int rlocal = wm * 64 + i * 16 + qd * 4 + r;
            const int grow   = rbase + rlocal;
            const int tr     = tgtL[rlocal];
            float m = BIGF;
            #pragma unroll
            for (int j = 0; j < 2; ++j) {
                const int clocal = wn * 32 + j * 16 + ln;
                const float val = csqL[clocal] - 2.0f * acc[i][j][r];
                if (cbase + clocal == tr) {
                    apval[grow] = val;                 // exactly one writer per row
                } else {
                    m = fminf(m, val);
                }
            }
            #pragma unroll
            for (int off = 1; off < 16; off <<= 1)     // min over 16 cols in-wave
                m = fminf(m, __shfl_xor(m, off));
            if (ln == 0) atomicMin(&ldsmin[rlocal], fkey(m));
        }
    }
    __syncthreads();
    if (tid < 128)
        partmin[(size_t)(rbase + tid) * NCT + ct] = finv(ldsmin[tid]);  // plain store
}

// -------------------------------------------------------------------------
// k3: finalize + reduce, single block. partmin rows are contiguous 8-float
// runs -> two float4 loads per row, fully coalesced.
// -------------------------------------------------------------------------
__global__ __launch_bounds__(1024) void k3_final(
    const float* __restrict__ rsq, const float* __restrict__ partmin,
    const float* __restrict__ apval, float* __restrict__ out)
{
    __shared__ float sl[1024];
    __shared__ float sp[1024];
    const int tid = threadIdx.x;
    float a = 0.0f, p = 0.0f;
    #pragma unroll
    for (int it = 0; it < NB / 1024; ++it) {
        const int r = it * 1024 + tid;
        const float4* pm = (const float4*)&partmin[(size_t)r * NCT];
        float4 m0 = pm[0], m1 = pm[1];
        float m = fminf(fminf(fminf(m0.x, m0.y), fminf(m0.z, m0.w)),
                        fminf(fminf(m1.x, m1.y), fminf(m1.z, m1.w)));
        float s  = rsq[r];
        float an = sqrtf(fmaxf(s + m,        1e-12f));
        float ap = sqrtf(fmaxf(s + apval[r], 1e-12f));
        a += fmaxf(0.0f, ap - an + MARGIN_F);
        p += (an > ap) ? 1.0f : 0.0f;
    }
    sl[tid] = a; sp[tid] = p;
    __syncthreads();
    #pragma unroll
    for (int s = 512; s > 0; s >>= 1) {
        if (tid < s) { sl[tid] += sl[tid + s]; sp[tid] += sp[tid + s]; }
        __syncthreads();
    }
    if (tid == 0) {
        out[0] = sl[0] / (float)NB;
        out[1] = sp[0] / (float)NB;
    }
}

extern "C" void kernel_launch(void* const* d_in, const int* in_sizes, int n_in,
                              void* d_out, int out_size, void* d_ws, size_t ws_size,
                              hipStream_t stream) {
    const float* inputs  = (const float*)d_in[0];
    const int*   targets = (const int*)d_in[1];
    const float* centers = (const float*)d_in[2];
    float* out = (float*)d_out;

    // ws layout (bytes):
    char* wp = (char*)d_ws;
    unsigned short* inB     = (unsigned short*)(wp);             // 8192*512*2 = 8388608
    unsigned short* cenB    = (unsigned short*)(wp + 8388608);   // 512*512*2  = 524288
    float*          rsq     = (float*)(wp + 8912896);            // 8192*4
    float*          csqv    = (float*)(wp + 8945664);            // 512*4
    unsigned*       counts  = (unsigned*)(wp + 8947712);         // 512*4
    float*          apval   = (float*)(wp + 8949760);            // 8192*4
    float*          partmin = (float*)(wp + 8982528);            // 8192*8*4 = 262144

    k0_prep<<<2177, 256, 0, stream>>>(inputs, targets, centers,
                                      inB, cenB, rsq, csqv, counts);
    k2_mfma<<<512, 256, 0, stream>>>(inB, cenB, targets, counts, csqv,
                                     partmin, apval);
    k3_final<<<1, 1024, 0, stream>>>(rsq, partmin, apval, out);
}